// Round 15
// baseline (45.868 us; speedup 1.0000x reference)
//
#include <hip/hip_runtime.h>
#include <math.h>

#define NP 16384   // spatial positions = 32*32*16
#define HDIM 32
#define WDIM 32
#define ZDIM 16

typedef short bf16x8 __attribute__((ext_vector_type(8)));
typedef unsigned short u16x8 __attribute__((ext_vector_type(8)));
typedef unsigned short u16x4 __attribute__((ext_vector_type(4)));
typedef float f32x4 __attribute__((ext_vector_type(4)));

__device__ __forceinline__ unsigned short f2bf(float f) {
    unsigned int u = __float_as_uint(f);
    return (unsigned short)((u + 0x7fffu + ((u >> 16) & 1u)) >> 16);
}

// pack 8 consecutive f32 -> bf16x8 (two float4 loads)
__device__ __forceinline__ bf16x8 cvt8(const float* __restrict__ p) {
    const float4 w0 = *(const float4*)p;
    const float4 w1 = *(const float4*)(p + 4);
    bf16x8 v;
    v[0] = (short)f2bf(w0.x); v[1] = (short)f2bf(w0.y);
    v[2] = (short)f2bf(w0.z); v[3] = (short)f2bf(w0.w);
    v[4] = (short)f2bf(w1.x); v[5] = (short)f2bf(w1.y);
    v[6] = (short)f2bf(w1.z); v[7] = (short)f2bf(w1.w);
    return v;
}

// ---------------------------------------------------------------------------
// Fused convert + QKV GEMM (identical to round 13).
// Block (512 thr, 8 waves) covers 64 positions.  T14 split staging; wave wv
// computes rows wv*48..+47 x 64 cols.  Outputs: Q[p][ch] (scaled), K[p][ch],
// VT[ch][p].  Grid 256 blocks.
// ---------------------------------------------------------------------------
__global__ __launch_bounds__(512) void qkv_fused(
    const float* __restrict__ x, const float* __restrict__ Wqkv,
    const float* __restrict__ bias,
    unsigned short* __restrict__ Qb, unsigned short* __restrict__ Kb,
    unsigned short* __restrict__ VTb)
{
    __shared__ __align__(16) unsigned char Xs[64 * 256];   // 16 KB

    const int tid = threadIdx.x;
    const int p0  = blockIdx.x * 64;

    // --- T14 stage-issue: x loads into registers (2 items x 8 floats)
    float xv0[8], xv1[8];
    {
        const int pl0 = tid & 63,            c00 = (tid >> 6) * 8;
        const int pl1 = (tid + 512) & 63,    c01 = ((tid + 512) >> 6) * 8;
        #pragma unroll
        for (int j = 0; j < 8; ++j) xv0[j] = x[(c00 + j) * NP + p0 + pl0];
        #pragma unroll
        for (int j = 0; j < 8; ++j) xv1[j] = x[(c01 + j) * NP + p0 + pl1];
    }

    const int lane = tid & 63;
    const int wv   = tid >> 6;
    const int l15  = lane & 15;
    const int kg   = lane >> 4;
    const int wrow = wv * 48;          // this wave's first output row

    // A fragments (3 row-tiles x 4 k-blocks) -- latency hides under x loads
    bf16x8 a[3][4];
    float  b4[3][4];
    #pragma unroll
    for (int t = 0; t < 3; ++t) {
        const int row = wrow + t * 16 + l15;
        #pragma unroll
        for (int kb = 0; kb < 4; ++kb)
            a[t][kb] = cvt8(&Wqkv[row * 128 + kb * 32 + kg * 8]);
        #pragma unroll
        for (int r = 0; r < 4; ++r)
            b4[t][r] = bias[wrow + t * 16 + kg * 4 + r];
    }

    // --- T14 stage-write: convert x and store to swizzled LDS
    {
        const int pl0 = tid & 63,            c00 = (tid >> 6) * 8;
        const int pl1 = (tid + 512) & 63,    c01 = ((tid + 512) >> 6) * 8;
        u16x8 v8;
        #pragma unroll
        for (int j = 0; j < 8; ++j) v8[j] = f2bf(xv0[j]);
        *(u16x8*)(Xs + pl0 * 256 + ((c00 * 2) ^ ((pl0 & 7) << 4))) = v8;
        #pragma unroll
        for (int j = 0; j < 8; ++j) v8[j] = f2bf(xv1[j]);
        *(u16x8*)(Xs + pl1 * 256 + ((c01 * 2) ^ ((pl1 & 7) << 4))) = v8;
    }
    __syncthreads();

    #pragma unroll
    for (int ct = 0; ct < 4; ++ct) {
        const int pl = ct * 16 + l15;
        bf16x8 bfr[4];
        #pragma unroll
        for (int kb = 0; kb < 4; ++kb) {
            const int byte = pl * 256 + ((kb * 64 + kg * 16) ^ ((pl & 7) << 4));
            bfr[kb] = *(const bf16x8*)(Xs + byte);
        }
        const int p = p0 + pl;
        #pragma unroll
        for (int t = 0; t < 3; ++t) {
            f32x4 acc = {0.f, 0.f, 0.f, 0.f};
            __builtin_amdgcn_s_setprio(1);
            #pragma unroll
            for (int kb = 0; kb < 4; ++kb)
                acc = __builtin_amdgcn_mfma_f32_16x16x32_bf16(a[t][kb], bfr[kb], acc, 0, 0, 0);
            __builtin_amdgcn_s_setprio(0);
            const int r0 = wrow + t * 16;
            const float rowscale = (r0 < 128) ? 0.17677669529663687f : 1.f;
            unsigned short hh[4];
            #pragma unroll
            for (int r = 0; r < 4; ++r)
                hh[r] = f2bf((acc[r] + b4[t][r]) * rowscale);
            if (r0 < 128) {
                u16x4 ph = {hh[0], hh[1], hh[2], hh[3]};
                *(u16x4*)&Qb[p * 128 + r0 + kg * 4] = ph;
            } else if (r0 < 256) {
                u16x4 ph = {hh[0], hh[1], hh[2], hh[3]};
                *(u16x4*)&Kb[p * 128 + (r0 - 128) + kg * 4] = ph;
            } else {
                #pragma unroll
                for (int r = 0; r < 4; ++r)
                    VTb[(r0 - 256 + kg * 4 + r) * NP + p] = hh[r];
            }
        }
    }
}

// ---------------------------------------------------------------------------
// Fused MFMA neighborhood attention + output projection, re-grained:
// Block = 4 waves (256 thr), block = one (h,w) column (16 positions), wave =
// one head.  Per-wave math identical to round 13.  LDS 26 KB -> more
// blocks/CU, smaller barrier scope.
// Phase 1: 16 q x 144 keys, S^T = mfma(K,Q), softmax, P -> swizzled LDS,
// PV = mfma(P, V^T) -> swizzled As tile [16 pos][128 ch].
// Phase 2: wave wv computes out rows wv*32..+31 = Wp . As + bp.
// Grid (32, 32), 256 threads.  setprio(1) wraps MFMA clusters (T5).
// ---------------------------------------------------------------------------
#define PROW 320               // 160 keys * 2 B per q-row
#define PWAVE (16 * PROW)      // 5120 B per wave

__global__ __launch_bounds__(256) void natten_proj(
    const unsigned short* __restrict__ Qb, const unsigned short* __restrict__ Kb,
    const unsigned short* __restrict__ VTb,
    const float* __restrict__ rpb,
    const float* __restrict__ Wp, const float* __restrict__ bp,
    float* __restrict__ out)
{
    __shared__ __align__(16) unsigned char Pl[4 * PWAVE];   // 20 KB
    __shared__ __align__(16) unsigned char As[16 * 256];    //  4 KB attn tile
    __shared__ float bias_s[500];                           //  2 KB (4 heads)

    const int tid  = threadIdx.x;
    const int h    = blockIdx.y;
    const int w    = blockIdx.x;
    const int wv   = tid >> 6;         // wave = head
    const int head = wv;
    const int lane = tid & 63;
    const int l15  = lane & 15;
    const int kg   = lane >> 4;

    #pragma unroll
    for (int i = tid; i < 500; i += 256) bias_s[i] = rpb[i];
    __syncthreads();

    const int hs = min(max(h - 1, 0), HDIM - 3);
    const int ws = min(max(w - 1, 0), WDIM - 3);
    const int rh0 = hs - h + 2, rw0 = ws - w + 2;
    const int pcol = (h * 32 + w) * 16;       // this block's 16 positions
    const int cb = head * 32;

    // --- phase-2 operands loaded early (independent; hides under phase 1)
    const int prow0 = wv * 32;                // projection rows: wv*32..+31
    bf16x8 aw[2][4];
    float  bpr[2][4];
    #pragma unroll
    for (int t = 0; t < 2; ++t) {
        const int ab = (prow0 + t * 16 + l15) * 128 + kg * 8;
        #pragma unroll
        for (int kb = 0; kb < 4; ++kb)
            aw[t][kb] = cvt8(&Wp[ab + kb * 32]);
        #pragma unroll
        for (int r = 0; r < 4; ++r)
            bpr[t][r] = bp[prow0 + t * 16 + kg * 4 + r];
    }

    const bf16x8 bq = *(const bf16x8*)&Qb[(pcol + l15) * 128 + cb + kg * 8];

    const int z  = l15;
    const int zs = min(max(z - 1, 0), ZDIM - 3);

    // per-lane z-window mask + clamped bias index (loop-invariant over g)
    int   idxc[4];
    float vmask[4];
    #pragma unroll
    for (int r = 0; r < 4; ++r) {
        const int zp = kg * 4 + r;
        const int dz = zp - z + 2;
        idxc[r]  = min(max(dz, 0), 4);
        vmask[r] = (zp >= zs && zp <= zs + 2) ? 1.f : 0.f;
    }
    float biasv[9][4];
    #pragma unroll
    for (int g = 0; g < 9; ++g) {
        const int bbase = head * 125 + ((rh0 + g / 3) * 5 + (rw0 + g % 3)) * 5;
        #pragma unroll
        for (int r = 0; r < 4; ++r)
            biasv[g][r] = bias_s[bbase + idxc[r]];
    }

    float sv[9][4];
    float m = -1e30f;
    __builtin_amdgcn_s_setprio(1);
    #pragma unroll
    for (int g = 0; g < 9; ++g) {
        const int dh = g / 3, dw = g % 3;
        const int pn = ((hs + dh) * 32 + (ws + dw)) * 16;
        const bf16x8 ak = *(const bf16x8*)&Kb[(pn + l15) * 128 + cb + kg * 8];
        f32x4 st = {0.f, 0.f, 0.f, 0.f};
        st = __builtin_amdgcn_mfma_f32_16x16x32_bf16(ak, bq, st, 0, 0, 0);
        #pragma unroll
        for (int r = 0; r < 4; ++r) {
            sv[g][r] = st[r] + biasv[g][r];
            m = fmaxf(m, sv[g][r]);
        }
    }
    __builtin_amdgcn_s_setprio(0);
    m = fmaxf(m, __shfl_xor(m, 16, 64));
    m = fmaxf(m, __shfl_xor(m, 32, 64));

    float sum = 0.f;
    #pragma unroll
    for (int g = 0; g < 9; ++g)
        #pragma unroll
        for (int r = 0; r < 4; ++r) {
            sv[g][r] = __expf(sv[g][r] - m) * vmask[r];
            sum += sv[g][r];
        }
    sum += __shfl_xor(sum, 16, 64);
    sum += __shfl_xor(sum, 32, 64);
    const float inv = 1.f / sum;

    unsigned char* Pw = &Pl[wv * PWAVE];
    #pragma unroll
    for (int g = 0; g < 9; ++g) {
        u16x4 pk;
        #pragma unroll
        for (int r = 0; r < 4; ++r) pk[r] = f2bf(sv[g][r]);
        const int off = (z * PROW + (16 * g + kg * 4) * 2) ^ ((z & 7) << 4);
        *(u16x4*)(Pw + off) = pk;
    }
    {   // zero-pad keys 144..159
        u16x4 zq = {0, 0, 0, 0};
        const int off = (z * PROW + (144 + kg * 4) * 2) ^ ((z & 7) << 4);
        *(u16x4*)(Pw + off) = zq;
    }

    float invr[4];
    #pragma unroll
    for (int r = 0; r < 4; ++r)
        invr[r] = __shfl(inv, (lane & 48) | (kg * 4 + r), 64);

    // PV -> attention output into swizzled LDS tile As [16 pos][128 ch]
    #pragma unroll
    for (int ct = 0; ct < 2; ++ct) {
        f32x4 acc = {0.f, 0.f, 0.f, 0.f};
        __builtin_amdgcn_s_setprio(1);
        #pragma unroll
        for (int kb = 0; kb < 5; ++kb) {
            const int off = (z * PROW + (kb * 32 + kg * 8) * 2) ^ ((z & 7) << 4);
            const bf16x8 ap = *(const bf16x8*)(Pw + off);
            const int ga = 2 * kb;
            const int gb = (2 * kb + 1 > 8) ? 8 : 2 * kb + 1;
            const int pna = ((hs + ga / 3) * 32 + (ws + ga % 3)) * 16;
            const int pnbv = ((hs + gb / 3) * 32 + (ws + gb % 3)) * 16;
            const int pn = (kg & 2) ? pnbv : pna;
            const int zoff = (kg & 1) * 8;
            const bf16x8 bv = *(const bf16x8*)&VTb[(cb + ct * 16 + l15) * NP + pn + zoff];
            acc = __builtin_amdgcn_mfma_f32_16x16x32_bf16(ap, bv, acc, 0, 0, 0);
        }
        __builtin_amdgcn_s_setprio(0);
        #pragma unroll
        for (int r = 0; r < 4; ++r) {
            const int pl = kg * 4 + r;                     // local position 0..15
            const int ch = cb + ct * 16 + l15;             // channel 0..127
            const int byte = pl * 256 + ((ch * 2) ^ ((pl & 7) << 4));
            *(unsigned short*)(As + byte) = f2bf(acc[r] * invr[r]);
        }
    }

    __syncthreads();

    // ---- Phase 2: projection.  Wave wv computes out rows wv*32..+31 for the
    // block's 16 positions.
    const int pl = l15;
    bf16x8 bh[4];
    #pragma unroll
    for (int kb = 0; kb < 4; ++kb) {
        const int byte = pl * 256 + ((kb * 64 + kg * 16) ^ ((pl & 7) << 4));
        bh[kb] = *(const bf16x8*)(As + byte);
    }
    #pragma unroll
    for (int t = 0; t < 2; ++t) {
        f32x4 acc = {0.f, 0.f, 0.f, 0.f};
        #pragma unroll
        for (int kb = 0; kb < 4; ++kb)
            acc = __builtin_amdgcn_mfma_f32_16x16x32_bf16(aw[t][kb], bh[kb], acc, 0, 0, 0);
        #pragma unroll
        for (int r = 0; r < 4; ++r)
            out[(prow0 + t * 16 + kg * 4 + r) * NP + pcol + l15] = acc[r] + bpr[t][r];
    }
}

// ---------------------------------------------------------------------------
extern "C" void kernel_launch(void* const* d_in, const int* in_sizes, int n_in,
                              void* d_out, int out_size, void* d_ws, size_t ws_size,
                              hipStream_t stream)
{
    const float* x    = (const float*)d_in[0];
    const float* Wqkv = (const float*)d_in[1];
    const float* bqkv = (const float*)d_in[2];
    const float* rpb  = (const float*)d_in[3];
    const float* Wp   = (const float*)d_in[4];
    const float* bp   = (const float*)d_in[5];
    float* out = (float*)d_out;

    unsigned short* base = (unsigned short*)d_ws;
    const size_t PL = (size_t)NP * 128;
    unsigned short* Qb  = base;            // [NP][128] bf16
    unsigned short* Kb  = base + 1 * PL;
    unsigned short* VTb = base + 2 * PL;   // [128][NP]

    qkv_fused<<<dim3(NP / 64), dim3(512), 0, stream>>>(
        x, Wqkv, bqkv, Qb, Kb, VTb);

    natten_proj<<<dim3(32, 32), dim3(256), 0, stream>>>(
        Qb, Kb, VTb, rpb, Wp, bp, out);
}

// Round 16
// 37.110 us; speedup vs baseline: 1.2360x; 1.2360x over previous
//
#include <hip/hip_runtime.h>
#include <math.h>

#define NP 16384   // spatial positions = 32*32*16
#define HDIM 32
#define WDIM 32
#define ZDIM 16

typedef short bf16x8 __attribute__((ext_vector_type(8)));
typedef unsigned short u16x8 __attribute__((ext_vector_type(8)));
typedef unsigned short u16x4 __attribute__((ext_vector_type(4)));
typedef float f32x4 __attribute__((ext_vector_type(4)));

__device__ __forceinline__ unsigned short f2bf(float f) {
    unsigned int u = __float_as_uint(f);
    return (unsigned short)((u + 0x7fffu + ((u >> 16) & 1u)) >> 16);
}

// pack 8 consecutive f32 -> bf16x8 (two float4 loads)
__device__ __forceinline__ bf16x8 cvt8(const float* __restrict__ p) {
    const float4 w0 = *(const float4*)p;
    const float4 w1 = *(const float4*)(p + 4);
    bf16x8 v;
    v[0] = (short)f2bf(w0.x); v[1] = (short)f2bf(w0.y);
    v[2] = (short)f2bf(w0.z); v[3] = (short)f2bf(w0.w);
    v[4] = (short)f2bf(w1.x); v[5] = (short)f2bf(w1.y);
    v[6] = (short)f2bf(w1.z); v[7] = (short)f2bf(w1.w);
    return v;
}

// ---------------------------------------------------------------------------
// Fused convert + QKV GEMM (round-13 exact).
// Block (512 thr, 8 waves) covers 64 positions.  T14 split staging; wave wv
// computes rows wv*48..+47 x 64 cols.  Outputs: Q[p][ch] (scaled), K[p][ch],
// VT[ch][p].  Grid 256 blocks.
// ---------------------------------------------------------------------------
__global__ __launch_bounds__(512) void qkv_fused(
    const float* __restrict__ x, const float* __restrict__ Wqkv,
    const float* __restrict__ bias,
    unsigned short* __restrict__ Qb, unsigned short* __restrict__ Kb,
    unsigned short* __restrict__ VTb)
{
    __shared__ __align__(16) unsigned char Xs[64 * 256];   // 16 KB

    const int tid = threadIdx.x;
    const int p0  = blockIdx.x * 64;

    // --- T14 stage-issue: x loads into registers (2 items x 8 floats)
    float xv0[8], xv1[8];
    {
        const int pl0 = tid & 63,            c00 = (tid >> 6) * 8;
        const int pl1 = (tid + 512) & 63,    c01 = ((tid + 512) >> 6) * 8;
        #pragma unroll
        for (int j = 0; j < 8; ++j) xv0[j] = x[(c00 + j) * NP + p0 + pl0];
        #pragma unroll
        for (int j = 0; j < 8; ++j) xv1[j] = x[(c01 + j) * NP + p0 + pl1];
    }

    const int lane = tid & 63;
    const int wv   = tid >> 6;
    const int l15  = lane & 15;
    const int kg   = lane >> 4;
    const int wrow = wv * 48;          // this wave's first output row

    // A fragments (3 row-tiles x 4 k-blocks) -- latency hides under x loads
    bf16x8 a[3][4];
    float  b4[3][4];
    #pragma unroll
    for (int t = 0; t < 3; ++t) {
        const int row = wrow + t * 16 + l15;
        #pragma unroll
        for (int kb = 0; kb < 4; ++kb)
            a[t][kb] = cvt8(&Wqkv[row * 128 + kb * 32 + kg * 8]);
        #pragma unroll
        for (int r = 0; r < 4; ++r)
            b4[t][r] = bias[wrow + t * 16 + kg * 4 + r];
    }

    // --- T14 stage-write: convert x and store to swizzled LDS
    {
        const int pl0 = tid & 63,            c00 = (tid >> 6) * 8;
        const int pl1 = (tid + 512) & 63,    c01 = ((tid + 512) >> 6) * 8;
        u16x8 v8;
        #pragma unroll
        for (int j = 0; j < 8; ++j) v8[j] = f2bf(xv0[j]);
        *(u16x8*)(Xs + pl0 * 256 + ((c00 * 2) ^ ((pl0 & 7) << 4))) = v8;
        #pragma unroll
        for (int j = 0; j < 8; ++j) v8[j] = f2bf(xv1[j]);
        *(u16x8*)(Xs + pl1 * 256 + ((c01 * 2) ^ ((pl1 & 7) << 4))) = v8;
    }
    __syncthreads();

    #pragma unroll
    for (int ct = 0; ct < 4; ++ct) {
        const int pl = ct * 16 + l15;
        bf16x8 bfr[4];
        #pragma unroll
        for (int kb = 0; kb < 4; ++kb) {
            const int byte = pl * 256 + ((kb * 64 + kg * 16) ^ ((pl & 7) << 4));
            bfr[kb] = *(const bf16x8*)(Xs + byte);
        }
        const int p = p0 + pl;
        #pragma unroll
        for (int t = 0; t < 3; ++t) {
            f32x4 acc = {0.f, 0.f, 0.f, 0.f};
            __builtin_amdgcn_s_setprio(1);
            #pragma unroll
            for (int kb = 0; kb < 4; ++kb)
                acc = __builtin_amdgcn_mfma_f32_16x16x32_bf16(a[t][kb], bfr[kb], acc, 0, 0, 0);
            __builtin_amdgcn_s_setprio(0);
            const int r0 = wrow + t * 16;
            const float rowscale = (r0 < 128) ? 0.17677669529663687f : 1.f;
            unsigned short hh[4];
            #pragma unroll
            for (int r = 0; r < 4; ++r)
                hh[r] = f2bf((acc[r] + b4[t][r]) * rowscale);
            if (r0 < 128) {
                u16x4 ph = {hh[0], hh[1], hh[2], hh[3]};
                *(u16x4*)&Qb[p * 128 + r0 + kg * 4] = ph;
            } else if (r0 < 256) {
                u16x4 ph = {hh[0], hh[1], hh[2], hh[3]};
                *(u16x4*)&Kb[p * 128 + (r0 - 128) + kg * 4] = ph;
            } else {
                #pragma unroll
                for (int r = 0; r < 4; ++r)
                    VTb[(r0 - 256 + kg * 4 + r) * NP + p] = hh[r];
            }
        }
    }
}

// ---------------------------------------------------------------------------
// Fused MFMA neighborhood attention + output projection (round-13 structure;
// rpb LDS-stage barrier moved AFTER the independent Wp/bq loads).
// Block = 8 waves (512 thr): wave wv -> (head = wv>>1, wcol = wv&1),
// covering all 4 heads of 32 positions.  Grid (16, 32).
// ---------------------------------------------------------------------------
#define PROW 320               // 160 keys * 2 B per q-row
#define PWAVE (16 * PROW)      // 5120 B per wave

__global__ __launch_bounds__(512) void natten_proj(
    const unsigned short* __restrict__ Qb, const unsigned short* __restrict__ Kb,
    const unsigned short* __restrict__ VTb,
    const float* __restrict__ rpb,
    const float* __restrict__ Wp, const float* __restrict__ bp,
    float* __restrict__ out)
{
    __shared__ __align__(16) unsigned char Pl[8 * PWAVE];   // 40 KB
    __shared__ __align__(16) unsigned char As[32 * 256];    //  8 KB attn tile
    __shared__ float bias_s[500];                           //  2 KB (4 heads)

    const int tid  = threadIdx.x;
    const int h    = blockIdx.y;
    const int wv   = tid >> 6;
    const int head = wv >> 1;
    const int wcol = wv & 1;
    const int w    = blockIdx.x * 2 + wcol;
    const int lane = tid & 63;
    const int l15  = lane & 15;
    const int kg   = lane >> 4;

    // issue rpb staging; barrier deferred until after independent loads
    if (tid < 500) bias_s[tid] = rpb[tid];

    const int hs = min(max(h - 1, 0), HDIM - 3);
    const int ws = min(max(w - 1, 0), WDIM - 3);
    const int rh0 = hs - h + 2, rw0 = ws - w + 2;
    const int pcolw = (h * 32 + w) * 16;      // this wave's 16 positions
    const int cb = head * 32;

    // --- phase-2 operands loaded early (independent; hides under phase 1)
    const int prow0 = wv * 16;                // projection output rows
    bf16x8 aw[4];
    {
        const int ab = (prow0 + l15) * 128 + kg * 8;
        #pragma unroll
        for (int kb = 0; kb < 4; ++kb)
            aw[kb] = cvt8(&Wp[ab + kb * 32]);
    }
    float bpr[4];
    #pragma unroll
    for (int r = 0; r < 4; ++r) bpr[r] = bp[prow0 + kg * 4 + r];

    const bf16x8 bq = *(const bf16x8*)&Qb[(pcolw + l15) * 128 + cb + kg * 8];

    __syncthreads();                          // bias_s now visible

    const int z  = l15;
    const int zs = min(max(z - 1, 0), ZDIM - 3);

    // per-lane z-window mask + clamped bias index (loop-invariant over g)
    int   idxc[4];
    float vmask[4];
    #pragma unroll
    for (int r = 0; r < 4; ++r) {
        const int zp = kg * 4 + r;
        const int dz = zp - z + 2;
        idxc[r]  = min(max(dz, 0), 4);
        vmask[r] = (zp >= zs && zp <= zs + 2) ? 1.f : 0.f;
    }
    float biasv[9][4];
    #pragma unroll
    for (int g = 0; g < 9; ++g) {
        const int bbase = head * 125 + ((rh0 + g / 3) * 5 + (rw0 + g % 3)) * 5;
        #pragma unroll
        for (int r = 0; r < 4; ++r)
            biasv[g][r] = bias_s[bbase + idxc[r]];
    }

    float sv[9][4];
    float m = -1e30f;
    __builtin_amdgcn_s_setprio(1);
    #pragma unroll
    for (int g = 0; g < 9; ++g) {
        const int dh = g / 3, dw = g % 3;
        const int pn = ((hs + dh) * 32 + (ws + dw)) * 16;
        const bf16x8 ak = *(const bf16x8*)&Kb[(pn + l15) * 128 + cb + kg * 8];
        f32x4 st = {0.f, 0.f, 0.f, 0.f};
        st = __builtin_amdgcn_mfma_f32_16x16x32_bf16(ak, bq, st, 0, 0, 0);
        #pragma unroll
        for (int r = 0; r < 4; ++r) {
            sv[g][r] = st[r] + biasv[g][r];
            m = fmaxf(m, sv[g][r]);
        }
    }
    __builtin_amdgcn_s_setprio(0);
    m = fmaxf(m, __shfl_xor(m, 16, 64));
    m = fmaxf(m, __shfl_xor(m, 32, 64));

    float sum = 0.f;
    #pragma unroll
    for (int g = 0; g < 9; ++g)
        #pragma unroll
        for (int r = 0; r < 4; ++r) {
            sv[g][r] = __expf(sv[g][r] - m) * vmask[r];
            sum += sv[g][r];
        }
    sum += __shfl_xor(sum, 16, 64);
    sum += __shfl_xor(sum, 32, 64);
    const float inv = 1.f / sum;

    unsigned char* Pw = &Pl[wv * PWAVE];
    #pragma unroll
    for (int g = 0; g < 9; ++g) {
        u16x4 pk;
        #pragma unroll
        for (int r = 0; r < 4; ++r) pk[r] = f2bf(sv[g][r]);
        const int off = (z * PROW + (16 * g + kg * 4) * 2) ^ ((z & 7) << 4);
        *(u16x4*)(Pw + off) = pk;
    }
    {   // zero-pad keys 144..159
        u16x4 zq = {0, 0, 0, 0};
        const int off = (z * PROW + (144 + kg * 4) * 2) ^ ((z & 7) << 4);
        *(u16x4*)(Pw + off) = zq;
    }

    float invr[4];
    #pragma unroll
    for (int r = 0; r < 4; ++r)
        invr[r] = __shfl(inv, (lane & 48) | (kg * 4 + r), 64);

    // PV -> attention output into swizzled LDS tile As
    #pragma unroll
    for (int ct = 0; ct < 2; ++ct) {
        f32x4 acc = {0.f, 0.f, 0.f, 0.f};
        __builtin_amdgcn_s_setprio(1);
        #pragma unroll
        for (int kb = 0; kb < 5; ++kb) {
            const int off = (z * PROW + (kb * 32 + kg * 8) * 2) ^ ((z & 7) << 4);
            const bf16x8 ap = *(const bf16x8*)(Pw + off);
            const int ga = 2 * kb;
            const int gb = (2 * kb + 1 > 8) ? 8 : 2 * kb + 1;
            const int pna = ((hs + ga / 3) * 32 + (ws + ga % 3)) * 16;
            const int pnbv = ((hs + gb / 3) * 32 + (ws + gb % 3)) * 16;
            const int pn = (kg & 2) ? pnbv : pna;
            const int zoff = (kg & 1) * 8;
            const bf16x8 bv = *(const bf16x8*)&VTb[(cb + ct * 16 + l15) * NP + pn + zoff];
            acc = __builtin_amdgcn_mfma_f32_16x16x32_bf16(ap, bv, acc, 0, 0, 0);
        }
        __builtin_amdgcn_s_setprio(0);
        #pragma unroll
        for (int r = 0; r < 4; ++r) {
            const int pl = wcol * 16 + kg * 4 + r;         // local position 0..31
            const int ch = cb + ct * 16 + l15;             // channel 0..127
            const int byte = pl * 256 + ((ch * 2) ^ ((pl & 7) << 4));
            *(unsigned short*)(As + byte) = f2bf(acc[r] * invr[r]);
        }
    }

    __syncthreads();

    // ---- Phase 2: projection.  Wave wv computes out rows prow0..+15 for the
    // block's 32 positions.
    const int pcol0 = (h * 32 + blockIdx.x * 2) * 16;      // block's first position

    #pragma unroll
    for (int ct = 0; ct < 2; ++ct) {
        const int pl = ct * 16 + l15;
        f32x4 acc = {0.f, 0.f, 0.f, 0.f};
        #pragma unroll
        for (int kb = 0; kb < 4; ++kb) {
            const int byte = pl * 256 + ((kb * 64 + kg * 16) ^ ((pl & 7) << 4));
            const bf16x8 bh = *(const bf16x8*)(As + byte);
            acc = __builtin_amdgcn_mfma_f32_16x16x32_bf16(aw[kb], bh, acc, 0, 0, 0);
        }
        #pragma unroll
        for (int r = 0; r < 4; ++r)
            out[(prow0 + kg * 4 + r) * NP + pcol0 + ct * 16 + l15] = acc[r] + bpr[r];
    }
}

// ---------------------------------------------------------------------------
extern "C" void kernel_launch(void* const* d_in, const int* in_sizes, int n_in,
                              void* d_out, int out_size, void* d_ws, size_t ws_size,
                              hipStream_t stream)
{
    const float* x    = (const float*)d_in[0];
    const float* Wqkv = (const float*)d_in[1];
    const float* bqkv = (const float*)d_in[2];
    const float* rpb  = (const float*)d_in[3];
    const float* Wp   = (const float*)d_in[4];
    const float* bp   = (const float*)d_in[5];
    float* out = (float*)d_out;

    unsigned short* base = (unsigned short*)d_ws;
    const size_t PL = (size_t)NP * 128;
    unsigned short* Qb  = base;            // [NP][128] bf16
    unsigned short* Kb  = base + 1 * PL;
    unsigned short* VTb = base + 2 * PL;   // [128][NP]

    qkv_fused<<<dim3(NP / 64), dim3(512), 0, stream>>>(
        x, Wqkv, bqkv, Qb, Kb, VTb);

    natten_proj<<<dim3(16, 32), dim3(512), 0, stream>>>(
        Qb, Kb, VTb, rpb, Wp, bp, out);
}